// Round 9
// baseline (44814.514 us; speedup 1.0000x reference)
//
#include <hip/hip_runtime.h>

#define NODES 1024
#define LAYERS 5
#define SEQ 2048
#define IN_DIM 30
#define OUT_DIM 12
#define SLOPE 0.01f
#define RING_D 16

typedef unsigned long long u64;

__device__ __forceinline__ float sigmoidf_(float x) { return 1.0f / (1.0f + expf(-x)); }

// ---------------- FC1: concat(sim,real,act) @ W1^T + b1, leaky ----------------
__global__ __launch_bounds__(256) void fc1_kernel(
    const float* __restrict__ sim, const float* __restrict__ realv,
    const float* __restrict__ act, const float* __restrict__ W1,
    const float* __restrict__ b1, float* __restrict__ x_out)
{
    int t = blockIdx.x;
    __shared__ float in_s[IN_DIM];
    int tid = threadIdx.x;
    if (tid < 12) in_s[tid] = sim[t * 12 + tid];
    else if (tid < 24) in_s[tid] = realv[t * 12 + (tid - 12)];
    else if (tid < 30) in_s[tid] = act[t * 6 + (tid - 24)];
    __syncthreads();
    for (int n = tid; n < NODES; n += 256) {
        float acc = b1[n];
        const float* w = W1 + n * IN_DIM;
        #pragma unroll
        for (int k = 0; k < IN_DIM; ++k) acc += w[k] * in_s[k];
        x_out[t * NODES + n] = acc > 0.f ? acc : SLOPE * acc;
    }
}

// ---------------- xproj: XP = X @ W^T + (b_ih + b_hh) ----------------
#define BM 64
#define BN 64
#define BK 16

__global__ __launch_bounds__(256) void xproj_kernel(
    const float* __restrict__ X, const float* __restrict__ W,
    const float* __restrict__ bih, const float* __restrict__ bhh,
    float* __restrict__ XP)
{
    const int GN = 4 * NODES;
    int bm = blockIdx.y;
    int bn = blockIdx.x;
    __shared__ float As[BK][BM];
    __shared__ float Bs[BK][BN];
    int tid = threadIdx.x;
    int tx = tid % 16, ty = tid / 16;
    int arow = tid / 4;
    int acol4 = (tid % 4) * 4;
    float acc[4][4] = {};

    for (int k0 = 0; k0 < NODES; k0 += BK) {
        float4 a = *(const float4*)&X[(size_t)(bm * BM + arow) * NODES + k0 + acol4];
        As[acol4 + 0][arow] = a.x; As[acol4 + 1][arow] = a.y;
        As[acol4 + 2][arow] = a.z; As[acol4 + 3][arow] = a.w;
        float4 b = *(const float4*)&W[(size_t)(bn * BN + arow) * NODES + k0 + acol4];
        Bs[acol4 + 0][arow] = b.x; Bs[acol4 + 1][arow] = b.y;
        Bs[acol4 + 2][arow] = b.z; Bs[acol4 + 3][arow] = b.w;
        __syncthreads();
        #pragma unroll
        for (int k = 0; k < BK; ++k) {
            float ra[4], rb[4];
            #pragma unroll
            for (int m = 0; m < 4; ++m) ra[m] = As[k][ty * 4 + m];
            #pragma unroll
            for (int n = 0; n < 4; ++n) rb[n] = Bs[k][tx * 4 + n];
            #pragma unroll
            for (int m = 0; m < 4; ++m)
                #pragma unroll
                for (int n = 0; n < 4; ++n)
                    acc[m][n] += ra[m] * rb[n];
        }
        __syncthreads();
    }
    #pragma unroll
    for (int m = 0; m < 4; ++m) {
        int t = bm * BM + ty * 4 + m;
        int g0 = bn * BN + tx * 4;
        float4 o;
        o.x = acc[m][0] + bih[g0 + 0] + bhh[g0 + 0];
        o.y = acc[m][1] + bih[g0 + 1] + bhh[g0 + 1];
        o.z = acc[m][2] + bih[g0 + 2] + bhh[g0 + 2];
        o.w = acc[m][3] + bih[g0 + 3] + bhh[g0 + 3];
        *(float4*)&XP[(size_t)t * GN + g0] = o;
    }
}

// ---- targeted re-poll gather: read 1024 {flag,h} slots, stash floats to LDS ----
__device__ __forceinline__ void gather_ring(u64* __restrict__ ring, int flag,
                                            float* __restrict__ dst, int lane)
{
    u64* sl = ring + (size_t)(flag % RING_D) * NODES;
    unsigned miss = 0xffffu;
    float vals[16];
    while (miss) {
        #pragma unroll
        for (int k = 0; k < 16; ++k) {
            if (miss & (1u << k)) {
                u64 x = __hip_atomic_load(&sl[lane + k * 64],
                                          __ATOMIC_RELAXED, __HIP_MEMORY_SCOPE_AGENT);
                if ((int)(x >> 32) == flag) {
                    vals[k] = __uint_as_float((unsigned)x);
                    miss &= ~(1u << k);
                }
            }
        }
    }
    #pragma unroll
    for (int k = 0; k < 16; ++k) dst[lane + k * 64] = vals[k];
}

// ---------------- Fused LSTM group (NL=1 or 2), gatherer-wave pipeline ----------------
// 256 blocks x (NL*4 + NL) waves. Compute wave w (< NL*4): group-layer lg=w>>2,
// unit j = blockIdx.x*4 + (w&3). Gatherer waves: wave NL*4 = G0 (ring[l0]),
// wave NL*4+1 = G1 (ring[l1], NL=2 only). Per iteration i (one __syncthreads):
//   lg0 computes step t=i      using hA[p] (= ring[l0] payload flag i; h0 at i=0)
//   lg1 computes step t=i-1    using hB[p] (own, flag i-1) and hA[p] (x, flag i)
//   G0 polls ring[l0] flag i+1 -> hA[p^1]   (serves BOTH lg0-own and lg1-x next iter)
//   G1 polls ring[l1] flag i   -> hB[p^1]
// Weights: Whh in registers (64/lane, unconditional use); lg1's Wih in LDS (64KB).
// Ring overwrite safety is structural: block barrier bounds skew to <=1 step << D,
// so no producer throttle. Publishes are relaxed 8B agent atomics {flag,payload}
// (payload rides with flag; publish is data-dependent on all consumed words).
__global__ __launch_bounds__(640, 2)
void lstm_group_kernel(
    const float* __restrict__ Wih,   // [L][4N][N] (global base)
    const float* __restrict__ Whh,   // [L][4N][N] (global base)
    const float* __restrict__ bih,   // [L][4N]
    const float* __restrict__ bhh,   // [L][4N]
    const float* __restrict__ XP,    // [SEQ][4N] first-group-layer input proj
    const float* __restrict__ h0,    // [L][N]
    const float* __restrict__ c0,    // [L][N]
    float* __restrict__ Yout,        // [SEQ][N] last-group-layer output
    u64* rings, int l_base, int NL)
{
    __shared__ float wih_lds[16][NODES];  // lg1's Wih rows: [(unit&3)*4+g][k]
    __shared__ float hA[2][NODES];        // ring[l0] payloads, parity-buffered
    __shared__ float hB[2][NODES];        // ring[l1] payloads

    const int tid = threadIdx.x;
    const int wave = tid >> 6, lane = tid & 63;
    const int nComp = NL * 4;

    u64* ring0 = rings + (size_t)l_base * RING_D * NODES;
    u64* ring1 = rings + (size_t)(l_base + NL - 1) * RING_D * NODES;

    const int n_iter = (NL == 2) ? (SEQ + 1) : SEQ;

    if (wave < nComp) {
        const int lg = wave >> 2;
        const int j = blockIdx.x * 4 + (wave & 3);
        const int l = l_base + lg;
        u64* ring_own = (lg == 0) ? ring0 : ring1;

        // stage Whh rows into registers (used every step -> stays resident)
        float whh[4][16];
        {
            const float* wp = Whh + (size_t)l * 4 * NODES * NODES;
            #pragma unroll
            for (int g = 0; g < 4; ++g)
                #pragma unroll
                for (int k = 0; k < 16; ++k)
                    whh[g][k] = wp[(size_t)(g * NODES + j) * NODES + lane + k * 64];
        }
        float bg[4] = {0.f, 0.f, 0.f, 0.f};
        float xpg[4] = {0.f, 0.f, 0.f, 0.f};
        if (lg == 0) {
            #pragma unroll
            for (int g = 0; g < 4; ++g) xpg[g] = XP[(size_t)0 * 4 * NODES + g * NODES + j];
        } else {
            // stage this unit's 4 Wih rows into LDS
            const float* wp = Wih + (size_t)l * 4 * NODES * NODES;
            #pragma unroll
            for (int g = 0; g < 4; ++g) {
                const float* src = wp + (size_t)(g * NODES + j) * NODES;
                float* dst = wih_lds[(wave & 3) * 4 + g];
                #pragma unroll
                for (int v = 0; v < 4; ++v) {
                    int idx = (lane + v * 64) * 4;
                    *(float4*)&dst[idx] = *(const float4*)&src[idx];
                }
            }
            #pragma unroll
            for (int g = 0; g < 4; ++g)
                bg[g] = bih[l * 4 * NODES + g * NODES + j] + bhh[l * 4 * NODES + g * NODES + j];
        }
        float c = c0[l * NODES + j];
        __syncthreads();  // wih_lds staged

        for (int i = 0; i < n_iter; ++i) {
            const int p = i & 1;
            const int t = (lg == 0) ? i : i - 1;
            if (t >= 0 && t < SEQ) {
                float gate[4] = {0.f, 0.f, 0.f, 0.f};
                if (t == 0) {
                    #pragma unroll
                    for (int k = 0; k < 16; ++k) {
                        float hh = h0[l * NODES + lane + k * 64];
                        #pragma unroll
                        for (int g = 0; g < 4; ++g) gate[g] += whh[g][k] * hh;
                    }
                } else {
                    const float* hb = (lg == 0) ? hA[p] : hB[p];
                    #pragma unroll
                    for (int k = 0; k < 16; ++k) {
                        float hh = hb[lane + k * 64];
                        #pragma unroll
                        for (int g = 0; g < 4; ++g) gate[g] += whh[g][k] * hh;
                    }
                }
                if (lg == 1) {
                    const int r0 = (wave & 3) * 4;
                    #pragma unroll
                    for (int k = 0; k < 16; ++k) {
                        float xx = hA[p][lane + k * 64];
                        #pragma unroll
                        for (int g = 0; g < 4; ++g)
                            gate[g] += wih_lds[r0 + g][lane + k * 64] * xx;
                    }
                }
                #pragma unroll
                for (int g = 0; g < 4; ++g) {
                    float acc = gate[g];
                    #pragma unroll
                    for (int off = 32; off > 0; off >>= 1) acc += __shfl_xor(acc, off);
                    gate[g] = acc + ((lg == 0) ? xpg[g] : bg[g]);
                }
                float ig = sigmoidf_(gate[0]);
                float fg = sigmoidf_(gate[1]);
                float gg = tanhf(gate[2]);
                float og = sigmoidf_(gate[3]);
                c = fg * c + ig * gg;
                float h = og * tanhf(c);

                if (lane == 0) {
                    u64 pv = ((u64)(unsigned)(t + 1) << 32) | (u64)__float_as_uint(h);
                    __hip_atomic_store(&ring_own[(size_t)((t + 1) % RING_D) * NODES + j], pv,
                                       __ATOMIC_RELAXED, __HIP_MEMORY_SCOPE_AGENT);
                    if (lg == NL - 1) Yout[(size_t)t * NODES + j] = h;
                }
                if (lg == 0 && t + 1 < SEQ) {
                    #pragma unroll
                    for (int g = 0; g < 4; ++g)
                        xpg[g] = XP[(size_t)(t + 1) * 4 * NODES + g * NODES + j];
                }
            }
            __syncthreads();
        }
    } else {
        const bool isG0 = (wave == nComp);
        __syncthreads();  // match staging barrier
        for (int i = 0; i < n_iter; ++i) {
            const int p = i & 1;
            if (isG0) {
                const bool act = (NL == 2) ? (i <= SEQ - 1) : (i <= SEQ - 2);
                if (act) gather_ring(ring0, i + 1, hA[p ^ 1], lane);
            } else {
                const bool act = (i >= 1 && i <= SEQ - 1);
                if (act) gather_ring(ring1, i, hB[p ^ 1], lane);
            }
            __syncthreads();
        }
    }
}

// ---------------- FC2: leaky(Y) @ W2^T + b2 ----------------
__global__ __launch_bounds__(256) void fc2_kernel(
    const float* __restrict__ Y, const float* __restrict__ W2,
    const float* __restrict__ b2, float* __restrict__ out)
{
    int t = blockIdx.x;
    __shared__ float ys[NODES];
    int tid = threadIdx.x;
    for (int n = tid; n < NODES; n += 256) {
        float v = Y[(size_t)t * NODES + n];
        ys[n] = v > 0.f ? v : SLOPE * v;
    }
    __syncthreads();
    int wave = tid >> 6, lane = tid & 63;
    for (int o = wave; o < OUT_DIM; o += 4) {
        float acc = 0.f;
        const float* w = W2 + o * NODES;
        #pragma unroll
        for (int k = 0; k < 16; ++k) acc += w[lane + k * 64] * ys[lane + k * 64];
        #pragma unroll
        for (int off = 32; off > 0; off >>= 1) acc += __shfl_xor(acc, off);
        if (lane == 0) out[t * OUT_DIM + o] = acc + b2[o];
    }
}

extern "C" void kernel_launch(void* const* d_in, const int* in_sizes, int n_in,
                              void* d_out, int out_size, void* d_ws, size_t ws_size,
                              hipStream_t stream) {
    const float* sim  = (const float*)d_in[0];
    const float* relv = (const float*)d_in[1];
    const float* act  = (const float*)d_in[2];
    const float* W1   = (const float*)d_in[3];
    const float* b1   = (const float*)d_in[4];
    const float* W_ih = (const float*)d_in[5];
    const float* W_hh = (const float*)d_in[6];
    const float* b_ih = (const float*)d_in[7];
    const float* b_hh = (const float*)d_in[8];
    const float* W2   = (const float*)d_in[9];
    const float* b2   = (const float*)d_in[10];
    const float* h0   = (const float*)d_in[11];
    const float* c0   = (const float*)d_in[12];
    float* out = (float*)d_out;

    char* ws = (char*)d_ws;
    float* xbuf = (float*)ws;                                   // 8 MB (FC1 out; later Y4)
    float* xp   = (float*)(ws + (size_t)8 * 1024 * 1024);       // 32 MB (XP, reused per group)
    float* ya   = (float*)(ws + (size_t)40 * 1024 * 1024);      // 8 MB (Y1, then Y3)
    u64*   rings = (u64*)(ws + (size_t)48 * 1024 * 1024);       // 640 KB

    // zero rings in-graph every launch -> no stale flags across replays
    hipMemsetAsync(rings, 0, (size_t)LAYERS * RING_D * NODES * sizeof(u64), stream);

    fc1_kernel<<<SEQ, 256, 0, stream>>>(sim, relv, act, W1, b1, xbuf);

    // ---- group [0,1]: 256 blocks x 640 threads ----
    xproj_kernel<<<dim3(4 * NODES / BN, SEQ / BM), 256, 0, stream>>>(
        xbuf, W_ih, b_ih, b_hh, xp);
    {
        int l_base = 0, nl = 2;
        void* args[] = { (void*)&W_ih, (void*)&W_hh, (void*)&b_ih, (void*)&b_hh,
                         (void*)&xp, (void*)&h0, (void*)&c0, (void*)&ya,
                         (void*)&rings, (void*)&l_base, (void*)&nl };
        hipLaunchCooperativeKernel((const void*)lstm_group_kernel,
                                   dim3(256), dim3(640), args, 0, stream);
    }

    // ---- group [2,3] ----
    xproj_kernel<<<dim3(4 * NODES / BN, SEQ / BM), 256, 0, stream>>>(
        ya, W_ih + (size_t)2 * 4 * NODES * NODES,
        b_ih + 2 * 4 * NODES, b_hh + 2 * 4 * NODES, xp);
    {
        int l_base = 2, nl = 2;
        void* args[] = { (void*)&W_ih, (void*)&W_hh, (void*)&b_ih, (void*)&b_hh,
                         (void*)&xp, (void*)&h0, (void*)&c0, (void*)&ya,
                         (void*)&rings, (void*)&l_base, (void*)&nl };
        hipLaunchCooperativeKernel((const void*)lstm_group_kernel,
                                   dim3(256), dim3(640), args, 0, stream);
    }

    // ---- group [4] ----
    xproj_kernel<<<dim3(4 * NODES / BN, SEQ / BM), 256, 0, stream>>>(
        ya, W_ih + (size_t)4 * 4 * NODES * NODES,
        b_ih + 4 * 4 * NODES, b_hh + 4 * 4 * NODES, xp);
    {
        int l_base = 4, nl = 1;
        void* args[] = { (void*)&W_ih, (void*)&W_hh, (void*)&b_ih, (void*)&b_hh,
                         (void*)&xp, (void*)&h0, (void*)&c0, (void*)&xbuf,
                         (void*)&rings, (void*)&l_base, (void*)&nl };
        hipLaunchCooperativeKernel((const void*)lstm_group_kernel,
                                   dim3(256), dim3(320), args, 0, stream);
    }

    fc2_kernel<<<SEQ, 256, 0, stream>>>(xbuf, W2, b2, out);
}

// Round 10
// 43182.663 us; speedup vs baseline: 1.0378x; 1.0378x over previous
//
#include <hip/hip_runtime.h>

#define NODES 1024
#define LAYERS 5
#define SEQ 2048
#define IN_DIM 30
#define OUT_DIM 12
#define SLOPE 0.01f
#define RING_D 16

typedef unsigned long long u64;

__device__ __forceinline__ float sigmoidf_(float x) { return 1.0f / (1.0f + expf(-x)); }

// ---------------- FC1: concat(sim,real,act) @ W1^T + b1, leaky ----------------
__global__ __launch_bounds__(256) void fc1_kernel(
    const float* __restrict__ sim, const float* __restrict__ realv,
    const float* __restrict__ act, const float* __restrict__ W1,
    const float* __restrict__ b1, float* __restrict__ x_out)
{
    int t = blockIdx.x;
    __shared__ float in_s[IN_DIM];
    int tid = threadIdx.x;
    if (tid < 12) in_s[tid] = sim[t * 12 + tid];
    else if (tid < 24) in_s[tid] = realv[t * 12 + (tid - 12)];
    else if (tid < 30) in_s[tid] = act[t * 6 + (tid - 24)];
    __syncthreads();
    for (int n = tid; n < NODES; n += 256) {
        float acc = b1[n];
        const float* w = W1 + n * IN_DIM;
        #pragma unroll
        for (int k = 0; k < IN_DIM; ++k) acc += w[k] * in_s[k];
        x_out[t * NODES + n] = acc > 0.f ? acc : SLOPE * acc;
    }
}

// ---------------- xproj: XP = X @ W^T + (b_ih + b_hh) ----------------
#define BM 64
#define BN 64
#define BK 16

__global__ __launch_bounds__(256) void xproj_kernel(
    const float* __restrict__ X, const float* __restrict__ W,
    const float* __restrict__ bih, const float* __restrict__ bhh,
    float* __restrict__ XP)
{
    const int GN = 4 * NODES;
    int bm = blockIdx.y;
    int bn = blockIdx.x;
    __shared__ float As[BK][BM];
    __shared__ float Bs[BK][BN];
    int tid = threadIdx.x;
    int tx = tid % 16, ty = tid / 16;
    int arow = tid / 4;
    int acol4 = (tid % 4) * 4;
    float acc[4][4] = {};

    for (int k0 = 0; k0 < NODES; k0 += BK) {
        float4 a = *(const float4*)&X[(size_t)(bm * BM + arow) * NODES + k0 + acol4];
        As[acol4 + 0][arow] = a.x; As[acol4 + 1][arow] = a.y;
        As[acol4 + 2][arow] = a.z; As[acol4 + 3][arow] = a.w;
        float4 b = *(const float4*)&W[(size_t)(bn * BN + arow) * NODES + k0 + acol4];
        Bs[acol4 + 0][arow] = b.x; Bs[acol4 + 1][arow] = b.y;
        Bs[acol4 + 2][arow] = b.z; Bs[acol4 + 3][arow] = b.w;
        __syncthreads();
        #pragma unroll
        for (int k = 0; k < BK; ++k) {
            float ra[4], rb[4];
            #pragma unroll
            for (int m = 0; m < 4; ++m) ra[m] = As[k][ty * 4 + m];
            #pragma unroll
            for (int n = 0; n < 4; ++n) rb[n] = Bs[k][tx * 4 + n];
            #pragma unroll
            for (int m = 0; m < 4; ++m)
                #pragma unroll
                for (int n = 0; n < 4; ++n)
                    acc[m][n] += ra[m] * rb[n];
        }
        __syncthreads();
    }
    #pragma unroll
    for (int m = 0; m < 4; ++m) {
        int t = bm * BM + ty * 4 + m;
        int g0 = bn * BN + tx * 4;
        float4 o;
        o.x = acc[m][0] + bih[g0 + 0] + bhh[g0 + 0];
        o.y = acc[m][1] + bih[g0 + 1] + bhh[g0 + 1];
        o.z = acc[m][2] + bih[g0 + 2] + bhh[g0 + 2];
        o.w = acc[m][3] + bih[g0 + 3] + bhh[g0 + 3];
        *(float4*)&XP[(size_t)t * GN + g0] = o;
    }
}

// ---------------- Fused LSTM group (NL = 2 or 3 layers), wavefront pipeline ----------------
// 256 blocks x NL*4 waves, cooperative, free-running (no in-loop barriers).
// Wave w: group-layer lg = w>>2, unit j = blockIdx.x*4 + (w&3); l = l_base+lg.
// lg0 consumes precomputed XP [SEQ][4N] (biases folded); lg>=1 consume the prev
// layer's ring on the fly, Wih rows staged in LDS (8 units x 4 rows x 4KB = 128KB).
// Whh rows live in registers (64 VGPR; polls are sequential w/ immediate
// accumulation to keep peak pressure ~110 so the compiler keeps them resident).
// Rings: rings[l][RING_D][NODES] of packed {flag=t+1, h} u64; relaxed 8B agent
// atomics only (payload rides with flag; publish is data-dependent on all
// gathered words -> no fences / no RMW).
// Consumer at step t: own flags == t (slot t%D); prev flags == t+1 (slot (t+1)%D).
// Producer throttle (non-last group-layer, t>=D): downstream unit j's published
// flag >= t+2-D before overwriting slot (t+1)%D. Own-layer lead bound is 1 << D.
__global__ __launch_bounds__(768)
void lstm_group_kernel(
    const float* __restrict__ Wih,   // [L][4N][N] (global base)
    const float* __restrict__ Whh,   // [L][4N][N] (global base)
    const float* __restrict__ bih,   // [L][4N]
    const float* __restrict__ bhh,   // [L][4N]
    const float* __restrict__ XP,    // [SEQ][4N] first-group-layer input proj
    const float* __restrict__ h0,    // [L][N]
    const float* __restrict__ c0,    // [L][N]
    float* __restrict__ Yout,        // [SEQ][N] last-group-layer output
    u64* rings, int l_base, int NL)
{
    __shared__ float wih_lds[8][4][NODES];  // local unit u = (lg-1)*4 + (w&3)

    const int tid = threadIdx.x;
    const int wave = tid >> 6, lane = tid & 63;
    const int lg = wave >> 2;
    const int j = blockIdx.x * 4 + (wave & 3);
    const int l = l_base + lg;
    const bool first = (lg == 0);
    const bool last  = (lg == NL - 1);

    // ---- Whh rows into registers ----
    float whh[4][16];
    {
        const float* wp = Whh + (size_t)l * 4 * NODES * NODES;
        #pragma unroll
        for (int g = 0; g < 4; ++g)
            #pragma unroll
            for (int k = 0; k < 16; ++k)
                whh[g][k] = wp[(size_t)(g * NODES + j) * NODES + lane + k * 64];
    }
    float bg[4] = {0.f, 0.f, 0.f, 0.f};
    float xpg[4] = {0.f, 0.f, 0.f, 0.f};
    const int u = (lg - 1) * 4 + (wave & 3);  // local LDS unit for lg>=1
    if (first) {
        #pragma unroll
        for (int g = 0; g < 4; ++g) xpg[g] = XP[(size_t)0 * 4 * NODES + g * NODES + j];
    } else {
        const float* wp = Wih + (size_t)l * 4 * NODES * NODES;
        #pragma unroll
        for (int g = 0; g < 4; ++g) {
            const float* src = wp + (size_t)(g * NODES + j) * NODES;
            float* dst = wih_lds[u][g];
            #pragma unroll
            for (int v = 0; v < 4; ++v) {
                int idx = (lane + v * 64) * 4;
                *(float4*)&dst[idx] = *(const float4*)&src[idx];
            }
        }
        #pragma unroll
        for (int g = 0; g < 4; ++g)
            bg[g] = bih[l * 4 * NODES + g * NODES + j] + bhh[l * 4 * NODES + g * NODES + j];
    }
    float c = c0[l * NODES + j];
    __syncthreads();  // wih_lds staged

    u64* ring_own  = rings + (size_t)l * RING_D * NODES;
    u64* ring_prev = rings + (size_t)(l > 0 ? l - 1 : 0) * RING_D * NODES;
    u64* ring_next = rings + (size_t)(!last ? l + 1 : l) * RING_D * NODES;

    for (int t = 0; t < SEQ; ++t) {
        // throttle prefetch (lane 0; normally already satisfied)
        u64 thr = 0;
        u64* tp = ring_next + (size_t)((t + 2) % RING_D) * NODES + j;
        const bool do_thr = (!last) && (t >= RING_D);
        if (do_thr && lane == 0)
            thr = __hip_atomic_load(tp, __ATOMIC_RELAXED, __HIP_MEMORY_SCOPE_AGENT);

        float gate[4] = {0.f, 0.f, 0.f, 0.f};

        // ---- own-layer h(t-1) contribution (poll own ring, then accumulate) ----
        if (t == 0) {
            #pragma unroll
            for (int k = 0; k < 16; ++k) {
                float hh = h0[l * NODES + lane + k * 64];
                #pragma unroll
                for (int g = 0; g < 4; ++g) gate[g] += whh[g][k] * hh;
            }
        } else {
            u64* so = ring_own + (size_t)(t % RING_D) * NODES;
            u64 vo[16];
            bool ok = false;
            while (!ok) {
                #pragma unroll
                for (int k = 0; k < 16; ++k)
                    vo[k] = __hip_atomic_load(&so[lane + k * 64],
                                              __ATOMIC_RELAXED, __HIP_MEMORY_SCOPE_AGENT);
                ok = true;
                #pragma unroll
                for (int k = 0; k < 16; ++k) ok = ok && ((int)(vo[k] >> 32) == t);
            }
            #pragma unroll
            for (int k = 0; k < 16; ++k) {
                float hh = __uint_as_float((unsigned)vo[k]);
                #pragma unroll
                for (int g = 0; g < 4; ++g) gate[g] += whh[g][k] * hh;
            }
        }

        // ---- prev-layer x(t) contribution (poll prev ring, accumulate via LDS Wih) ----
        if (!first) {
            u64* si = ring_prev + (size_t)((t + 1) % RING_D) * NODES;
            u64 vi[16];
            bool ok = false;
            while (!ok) {
                #pragma unroll
                for (int k = 0; k < 16; ++k)
                    vi[k] = __hip_atomic_load(&si[lane + k * 64],
                                              __ATOMIC_RELAXED, __HIP_MEMORY_SCOPE_AGENT);
                ok = true;
                #pragma unroll
                for (int k = 0; k < 16; ++k) ok = ok && ((int)(vi[k] >> 32) == t + 1);
            }
            #pragma unroll
            for (int k = 0; k < 16; ++k) {
                float xx = __uint_as_float((unsigned)vi[k]);
                #pragma unroll
                for (int g = 0; g < 4; ++g)
                    gate[g] += wih_lds[u][g][lane + k * 64] * xx;
            }
        }

        // ---- reduce + activations ----
        #pragma unroll
        for (int g = 0; g < 4; ++g) {
            float acc = gate[g];
            #pragma unroll
            for (int off = 32; off > 0; off >>= 1) acc += __shfl_xor(acc, off);
            gate[g] = acc + (first ? xpg[g] : bg[g]);
        }

        float ig = sigmoidf_(gate[0]);
        float fg = sigmoidf_(gate[1]);
        float gg = tanhf(gate[2]);
        float og = sigmoidf_(gate[3]);
        c = fg * c + ig * gg;
        float h = og * tanhf(c);

        if (lane == 0) {
            if (do_thr) {
                int thresh = t + 2 - RING_D;
                u64 tv = thr;
                while ((int)(tv >> 32) < thresh)
                    tv = __hip_atomic_load(tp, __ATOMIC_RELAXED, __HIP_MEMORY_SCOPE_AGENT);
            }
            u64 pv = ((u64)(unsigned)(t + 1) << 32) | (u64)__float_as_uint(h);
            __hip_atomic_store(&ring_own[(size_t)((t + 1) % RING_D) * NODES + j], pv,
                               __ATOMIC_RELAXED, __HIP_MEMORY_SCOPE_AGENT);
            if (last) Yout[(size_t)t * NODES + j] = h;
        }

        if (first && t + 1 < SEQ) {
            #pragma unroll
            for (int g = 0; g < 4; ++g)
                xpg[g] = XP[(size_t)(t + 1) * 4 * NODES + g * NODES + j];
        }
    }
}

// ---------------- FC2: leaky(Y) @ W2^T + b2 ----------------
__global__ __launch_bounds__(256) void fc2_kernel(
    const float* __restrict__ Y, const float* __restrict__ W2,
    const float* __restrict__ b2, float* __restrict__ out)
{
    int t = blockIdx.x;
    __shared__ float ys[NODES];
    int tid = threadIdx.x;
    for (int n = tid; n < NODES; n += 256) {
        float v = Y[(size_t)t * NODES + n];
        ys[n] = v > 0.f ? v : SLOPE * v;
    }
    __syncthreads();
    int wave = tid >> 6, lane = tid & 63;
    for (int o = wave; o < OUT_DIM; o += 4) {
        float acc = 0.f;
        const float* w = W2 + o * NODES;
        #pragma unroll
        for (int k = 0; k < 16; ++k) acc += w[lane + k * 64] * ys[lane + k * 64];
        #pragma unroll
        for (int off = 32; off > 0; off >>= 1) acc += __shfl_xor(acc, off);
        if (lane == 0) out[t * OUT_DIM + o] = acc + b2[o];
    }
}

extern "C" void kernel_launch(void* const* d_in, const int* in_sizes, int n_in,
                              void* d_out, int out_size, void* d_ws, size_t ws_size,
                              hipStream_t stream) {
    const float* sim  = (const float*)d_in[0];
    const float* relv = (const float*)d_in[1];
    const float* act  = (const float*)d_in[2];
    const float* W1   = (const float*)d_in[3];
    const float* b1   = (const float*)d_in[4];
    const float* W_ih = (const float*)d_in[5];
    const float* W_hh = (const float*)d_in[6];
    const float* b_ih = (const float*)d_in[7];
    const float* b_hh = (const float*)d_in[8];
    const float* W2   = (const float*)d_in[9];
    const float* b2   = (const float*)d_in[10];
    const float* h0   = (const float*)d_in[11];
    const float* c0   = (const float*)d_in[12];
    float* out = (float*)d_out;

    char* ws = (char*)d_ws;
    float* xbuf = (float*)ws;                                   // 8 MB (FC1 out; later Y4)
    float* xp   = (float*)(ws + (size_t)8 * 1024 * 1024);       // 32 MB (XP, per group)
    float* ya   = (float*)(ws + (size_t)40 * 1024 * 1024);      // 8 MB (Y2)
    u64*   rings = (u64*)(ws + (size_t)48 * 1024 * 1024);       // 640 KB

    // zero rings in-graph every launch -> no stale flags across replays
    hipMemsetAsync(rings, 0, (size_t)LAYERS * RING_D * NODES * sizeof(u64), stream);

    fc1_kernel<<<SEQ, 256, 0, stream>>>(sim, relv, act, W1, b1, xbuf);

    // ---- group [0,1,2]: 256 blocks x 768 threads ----
    xproj_kernel<<<dim3(4 * NODES / BN, SEQ / BM), 256, 0, stream>>>(
        xbuf, W_ih, b_ih, b_hh, xp);
    {
        int l_base = 0, nl = 3;
        void* args[] = { (void*)&W_ih, (void*)&W_hh, (void*)&b_ih, (void*)&b_hh,
                         (void*)&xp, (void*)&h0, (void*)&c0, (void*)&ya,
                         (void*)&rings, (void*)&l_base, (void*)&nl };
        hipLaunchCooperativeKernel((const void*)lstm_group_kernel,
                                   dim3(256), dim3(768), args, 0, stream);
    }

    // ---- group [3,4]: 256 blocks x 512 threads ----
    xproj_kernel<<<dim3(4 * NODES / BN, SEQ / BM), 256, 0, stream>>>(
        ya, W_ih + (size_t)3 * 4 * NODES * NODES,
        b_ih + 3 * 4 * NODES, b_hh + 3 * 4 * NODES, xp);
    {
        int l_base = 3, nl = 2;
        void* args[] = { (void*)&W_ih, (void*)&W_hh, (void*)&b_ih, (void*)&b_hh,
                         (void*)&xp, (void*)&h0, (void*)&c0, (void*)&xbuf,
                         (void*)&rings, (void*)&l_base, (void*)&nl };
        hipLaunchCooperativeKernel((const void*)lstm_group_kernel,
                                   dim3(256), dim3(512), args, 0, stream);
    }

    fc2_kernel<<<SEQ, 256, 0, stream>>>(xbuf, W2, b2, out);
}